// Round 2
// baseline (641.741 us; speedup 1.0000x reference)
//
#include <hip/hip_runtime.h>

typedef _Float16 half8  __attribute__((ext_vector_type(8)));
typedef _Float16 half4v __attribute__((ext_vector_type(4)));
typedef float    f32x4  __attribute__((ext_vector_type(4)));

#define GAT_SLOPE 0.2f
#define N_SRC0 500000
#define N_DST0 65536
#define N_DST1 8192
#define E0 1048576
#define E1 131072
#define H 4

__device__ __forceinline__ float leaky(float x) { return x >= 0.f ? x : GAT_SLOPE * x; }

// out[k*4+h] = sum_d W[k*(4D) + h*D + d] * a[h*D + d]
__global__ void collapse_kernel(const float* __restrict__ W, const float* __restrict__ a,
                                float* __restrict__ out, int K, int D) {
  int i = blockIdx.x * 256 + threadIdx.x;
  if (i >= K * 4) return;
  int k = i >> 2, h = i & 3;
  int N = 4 * D;
  float s = 0.f;
  for (int d = 0; d < D; ++d) s += W[(size_t)k * N + h * D + d] * a[h * D + d];
  out[i] = s;
}

// WT[n*K+k] = (fp16)W[k*N+n]
__global__ void transposeW_kernel(const float* __restrict__ W, _Float16* __restrict__ WT,
                                  int K, int N) {
  int i = blockIdx.x * 256 + threadIdx.x;
  if (i >= N * K) return;
  int nrow = i / K, k = i - nrow * K;
  WT[i] = (_Float16)W[(size_t)k * N + nrow];
}

// BTs[n*1024 + h*256 + k] = (n<47) ? 0.25*Ws1[k*188 + h*47 + n] : 0   (64 x 1024)
__global__ void wstack_kernel(const float* __restrict__ W, _Float16* __restrict__ BTs) {
  int i = blockIdx.x * 256 + threadIdx.x;  // i < 64*1024
  int n = i >> 10, kk = i & 1023;
  int h = kk >> 8, k = kk & 255;
  BTs[i] = (n < 47) ? (_Float16)(0.25f * W[(size_t)k * 188 + h * 47 + n]) : (_Float16)0.f;
}

// WLR[n*K+k]: n<4 -> wl[k*4+n]; n in [4,8) -> wr[k*4+n-4]; else 0.  (16 x K fp16)
__global__ void wlr_stack_kernel(const float* __restrict__ wl, const float* __restrict__ wr,
                                 _Float16* __restrict__ out, int K) {
  int i = blockIdx.x * 256 + threadIdx.x;
  if (i >= 16 * K) return;
  int n = i / K, k = i - n * K;
  float v = 0.f;
  if (n < 4) v = wl[k * 4 + n];
  else if (n < 8) v = wr[k * 4 + n - 4];
  out[i] = (_Float16)v;
}

// seg[d] = first edge index with dst >= d ; seg[nseg] = E (dst sorted ascending)
__global__ void seg_starts_kernel(const int* __restrict__ dst, int E, int nseg,
                                  int* __restrict__ seg) {
  int i = blockIdx.x * 256 + threadIdx.x;
  if (i > E) return;
  int lo = (i == 0) ? 0 : dst[i - 1] + 1;
  int hi = (i == E) ? nseg : dst[i];
  for (int d = lo; d <= hi; ++d) seg[d] = i;
}

// edge-parallel: alpha[e][h] = exp(leaky(el[src[e]][h] + er[dst[e]][h]))
// (no max-subtraction: |e| <~ 2 with 0.05-scale weights, exp overflow-safe in fp32)
__global__ __launch_bounds__(256) void score_kernel(
    const int* __restrict__ src, const int* __restrict__ dst,
    const float* __restrict__ el, const float* __restrict__ er,
    float* __restrict__ alpha, int E) {
  int e = blockIdx.x * 256 + threadIdx.x;
  if (e >= E) return;
  int s = src[e], d = dst[e];
  float4 e4 = *(const float4*)(el + (size_t)s * 4);
  float4 r4 = *(const float4*)(er + (size_t)d * 4);
  float4 o;
  o.x = __expf(leaky(e4.x + r4.x));
  o.y = __expf(leaky(e4.y + r4.y));
  o.z = __expf(leaky(e4.z + r4.z));
  o.w = __expf(leaky(e4.w + r4.w));
  *(float4*)(alpha + (size_t)e * 4) = o;
}

// streaming: x fp32 -> xh fp16 (global), + MFMA el0/er0 = x @ WLR0(128x16)
__global__ __launch_bounds__(256) void cvt_elr_mfma_kernel(
    const float* __restrict__ x, const _Float16* __restrict__ WLR,
    _Float16* __restrict__ xh, float* __restrict__ el, float* __restrict__ er,
    int M, int n_dst) {
  __shared__ _Float16 As[128 * 128];
  const int t = threadIdx.x, lane = t & 63, wid = t >> 6;
  const int m0 = blockIdx.x * 128;
  for (int i = 0; i < 8; ++i) {
    int c = t + 256 * i;
    int row = c >> 4, j = c & 15;
    int gr = m0 + row;
    half8 va = {};
    if (gr < M) {
      float4 f0 = *(const float4*)(x + (size_t)gr * 128 + j * 8);
      float4 f1 = *(const float4*)(x + (size_t)gr * 128 + j * 8 + 4);
      va[0] = (_Float16)f0.x; va[1] = (_Float16)f0.y;
      va[2] = (_Float16)f0.z; va[3] = (_Float16)f0.w;
      va[4] = (_Float16)f1.x; va[5] = (_Float16)f1.y;
      va[6] = (_Float16)f1.z; va[7] = (_Float16)f1.w;
      *(half8*)(xh + (size_t)gr * 128 + j * 8) = va;
    }
    *(half8*)(&As[row * 128 + ((j ^ (row & 7)) << 3)]) = va;
  }
  half8 bf[4];
  for (int kc = 0; kc < 4; ++kc)
    bf[kc] = *(const half8*)(WLR + (lane & 15) * 128 + kc * 32 + (lane >> 4) * 8);
  __syncthreads();
  f32x4 acc[2] = {};
  for (int rt = 0; rt < 2; ++rt) {
    int row = (wid * 2 + rt) * 16 + (lane & 15);
    for (int kc = 0; kc < 4; ++kc) {
      int chunk = kc * 4 + (lane >> 4);
      half8 af = *(const half8*)(&As[row * 128 + ((chunk ^ (row & 7)) << 3)]);
      acc[rt] = __builtin_amdgcn_mfma_f32_16x16x32_f16(af, bf[kc], acc[rt], 0, 0, 0);
    }
  }
  int col = lane & 15, quad = lane >> 4;
  for (int rt = 0; rt < 2; ++rt)
    for (int r = 0; r < 4; ++r) {
      int row = m0 + (wid * 2 + rt) * 16 + quad * 4 + r;
      if (row < M) {
        if (col < 4) el[(size_t)row * 4 + col] = acc[rt][r];
        else if (col < 8 && row < n_dst) er[(size_t)row * 4 + col - 4] = acc[rt][r];
      }
    }
}

// layer-0 aggregation, wave-per-node (4 nodes / 256-thr block), no LDS, no barriers.
// pass A: lane i holds alpha[s0+i] (float4) in regs, butterfly-sum -> sinv
// pass B: two 32-lane groups stream edges; alpha via __shfl from owning lane
__global__ __launch_bounds__(256) void agg0w_kernel(
    const int* __restrict__ src, const int* __restrict__ seg,
    const float* __restrict__ alpha, const _Float16* __restrict__ xh,
    _Float16* __restrict__ axh) {
  const int lane = threadIdx.x & 63, w = threadIdx.x >> 6;
  const int n = blockIdx.x * 4 + w;
  int s0 = seg[n], s1 = seg[n + 1], len = s1 - s0;
  float a0 = 0.f, a1 = 0.f, a2 = 0.f, a3 = 0.f;
  float t0 = 0.f, t1 = 0.f, t2 = 0.f, t3 = 0.f;
  if (lane < len) {
    float4 v = *(const float4*)(alpha + (size_t)(s0 + lane) * 4);
    a0 = v.x; a1 = v.y; a2 = v.z; a3 = v.w;
    t0 = v.x; t1 = v.y; t2 = v.z; t3 = v.w;
  }
  for (int idx = 64 + lane; idx < len; idx += 64) {
    float4 v = *(const float4*)(alpha + (size_t)(s0 + idx) * 4);
    t0 += v.x; t1 += v.y; t2 += v.z; t3 += v.w;
  }
#pragma unroll
  for (int off = 32; off; off >>= 1) {
    t0 += __shfl_xor(t0, off); t1 += __shfl_xor(t1, off);
    t2 += __shfl_xor(t2, off); t3 += __shfl_xor(t3, off);
  }
  float sinv[4];
  sinv[0] = t0 > 0.f ? 1.f / t0 : 0.f;
  sinv[1] = t1 > 0.f ? 1.f / t1 : 0.f;
  sinv[2] = t2 > 0.f ? 1.f / t2 : 0.f;
  sinv[3] = t3 > 0.f ? 1.f / t3 : 0.f;
  const int g = lane >> 5, ci = lane & 31;
  float A[4][4] = {};
  int iters = (len + 1) >> 1;
  for (int k = 0; k < iters; ++k) {
    int idx = g + 2 * k;
    int sl = idx < 64 ? idx : 0;
    float ah0 = __shfl(a0, sl), ah1 = __shfl(a1, sl);
    float ah2 = __shfl(a2, sl), ah3 = __shfl(a3, sl);
    if (idx >= 64 && idx < len) {
      float4 v = *(const float4*)(alpha + (size_t)(s0 + idx) * 4);
      ah0 = v.x; ah1 = v.y; ah2 = v.z; ah3 = v.w;
    }
    if (idx < len) {
      int sidx = src[s0 + idx];
      half4v xv = *(const half4v*)(xh + (size_t)sidx * 128 + ci * 4);
#pragma unroll
      for (int c = 0; c < 4; ++c) {
        float xc = (float)xv[c];
        A[0][c] += ah0 * xc; A[1][c] += ah1 * xc;
        A[2][c] += ah2 * xc; A[3][c] += ah3 * xc;
      }
    }
  }
#pragma unroll
  for (int h = 0; h < 4; ++h)
#pragma unroll
    for (int c = 0; c < 4; ++c) A[h][c] += __shfl_xor(A[h][c], 32);
  if (g == 0) {
#pragma unroll
    for (int h = 0; h < 4; ++h) {
      half4v o;
#pragma unroll
      for (int c = 0; c < 4; ++c) o[c] = (_Float16)(A[h][c] * sinv[h]);
      *(half4v*)(axh + ((size_t)n * 4 + h) * 128 + ci * 4) = o;
    }
  }
}

// layer-1 aggregation: same wave-per-node structure, 8 ch/lane over 256 cols
__global__ __launch_bounds__(256) void agg1w_kernel(
    const int* __restrict__ src, const int* __restrict__ seg,
    const float* __restrict__ alpha, const _Float16* __restrict__ h0,
    _Float16* __restrict__ axh1) {
  const int lane = threadIdx.x & 63, w = threadIdx.x >> 6;
  const int n = blockIdx.x * 4 + w;
  int s0 = seg[n], s1 = seg[n + 1], len = s1 - s0;
  float a0 = 0.f, a1 = 0.f, a2 = 0.f, a3 = 0.f;
  float t0 = 0.f, t1 = 0.f, t2 = 0.f, t3 = 0.f;
  if (lane < len) {
    float4 v = *(const float4*)(alpha + (size_t)(s0 + lane) * 4);
    a0 = v.x; a1 = v.y; a2 = v.z; a3 = v.w;
    t0 = v.x; t1 = v.y; t2 = v.z; t3 = v.w;
  }
  for (int idx = 64 + lane; idx < len; idx += 64) {
    float4 v = *(const float4*)(alpha + (size_t)(s0 + idx) * 4);
    t0 += v.x; t1 += v.y; t2 += v.z; t3 += v.w;
  }
#pragma unroll
  for (int off = 32; off; off >>= 1) {
    t0 += __shfl_xor(t0, off); t1 += __shfl_xor(t1, off);
    t2 += __shfl_xor(t2, off); t3 += __shfl_xor(t3, off);
  }
  float sinv[4];
  sinv[0] = t0 > 0.f ? 1.f / t0 : 0.f;
  sinv[1] = t1 > 0.f ? 1.f / t1 : 0.f;
  sinv[2] = t2 > 0.f ? 1.f / t2 : 0.f;
  sinv[3] = t3 > 0.f ? 1.f / t3 : 0.f;
  const int g = lane >> 5, ci = lane & 31;
  float A[4][8] = {};
  int iters = (len + 1) >> 1;
  for (int k = 0; k < iters; ++k) {
    int idx = g + 2 * k;
    int sl = idx < 64 ? idx : 0;
    float ah0 = __shfl(a0, sl), ah1 = __shfl(a1, sl);
    float ah2 = __shfl(a2, sl), ah3 = __shfl(a3, sl);
    if (idx >= 64 && idx < len) {
      float4 v = *(const float4*)(alpha + (size_t)(s0 + idx) * 4);
      ah0 = v.x; ah1 = v.y; ah2 = v.z; ah3 = v.w;
    }
    if (idx < len) {
      int sidx = src[s0 + idx];
      half8 xv = *(const half8*)(h0 + (size_t)sidx * 256 + ci * 8);
#pragma unroll
      for (int c = 0; c < 8; ++c) {
        float xc = (float)xv[c];
        A[0][c] += ah0 * xc; A[1][c] += ah1 * xc;
        A[2][c] += ah2 * xc; A[3][c] += ah3 * xc;
      }
    }
  }
#pragma unroll
  for (int h = 0; h < 4; ++h)
#pragma unroll
    for (int c = 0; c < 8; ++c) A[h][c] += __shfl_xor(A[h][c], 32);
  if (g == 0) {
#pragma unroll
    for (int h = 0; h < 4; ++h) {
      half8 o;
#pragma unroll
      for (int c = 0; c < 8; ++c) o[c] = (_Float16)(A[h][c] * sinv[h]);
      *(half8*)(axh1 + ((size_t)n * 4 + h) * 256 + ci * 8) = o;
    }
  }
}

// h0[m, h*64+d] = relu( axh[m,h,:] @ BT0[h*64+d, :] + b0 ), all 4 heads per block,
// FUSED epilogue: el1[m][hh] = sum_c h0[m,c]*wl1[c*4+hh], er1 likewise (rows < N_DST1).
// grid (N_DST0/128), block 256.
__global__ __launch_bounds__(256) void gemm_h0_kernel(
    const _Float16* __restrict__ axh, const _Float16* __restrict__ BT,
    const float* __restrict__ b, const float* __restrict__ wl1,
    const float* __restrict__ wr1, _Float16* __restrict__ h0,
    float* __restrict__ el1, float* __restrict__ er1) {
  __shared__ _Float16 As[128 * 128];
  __shared__ _Float16 Bs[64 * 128];
  const int t = threadIdx.x, lane = t & 63, wid = t >> 6;
  const int m0 = blockIdx.x * 128;
  const int cl = lane & 15, quad = lane >> 4;
  const int wm = wid * 32;
  f32x4 el1p[2][4] = {}, er1p[2][4] = {};
  for (int h = 0; h < 4; ++h) {
    for (int i = 0; i < 8; ++i) {
      int c = t + 256 * i, row = c >> 4, j = c & 15;
      int sw = ((j ^ (row & 7)) << 3);
      *(half8*)(&As[row * 128 + sw]) =
          *(const half8*)(axh + ((size_t)(m0 + row) * 4 + h) * 128 + j * 8);
    }
    for (int i = 0; i < 4; ++i) {
      int c = t + 256 * i, row = c >> 4, j = c & 15;
      int sw = ((j ^ (row & 7)) << 3);
      *(half8*)(&Bs[row * 128 + sw]) =
          *(const half8*)(BT + (size_t)(h * 64 + row) * 128 + j * 8);
    }
    __syncthreads();
    f32x4 acc[2][4] = {};
    for (int ks = 0; ks < 4; ++ks) {
      int kc = ks * 4 + quad;
      half8 af[2], bf[4];
      for (int i = 0; i < 2; ++i) {
        int ra = wm + 16 * i + cl;
        af[i] = *(const half8*)(&As[ra * 128 + ((kc ^ (ra & 7)) << 3)]);
      }
      for (int j2 = 0; j2 < 4; ++j2) {
        int rb = 16 * j2 + cl;
        bf[j2] = *(const half8*)(&Bs[rb * 128 + ((kc ^ (rb & 7)) << 3)]);
      }
      for (int i = 0; i < 2; ++i)
        for (int j2 = 0; j2 < 4; ++j2)
          acc[i][j2] = __builtin_amdgcn_mfma_f32_16x16x32_f16(af[i], bf[j2], acc[i][j2], 0, 0, 0);
    }
    __syncthreads();
    for (int j2 = 0; j2 < 4; ++j2) {
      int gcol = h * 64 + 16 * j2 + cl;
      float bias = b[gcol];
      f32x4 wlv = *(const f32x4*)(wl1 + (size_t)gcol * 4);
      f32x4 wrv = *(const f32x4*)(wr1 + (size_t)gcol * 4);
      for (int i = 0; i < 2; ++i) {
        int r0 = m0 + wm + 16 * i + quad * 4;
        for (int r = 0; r < 4; ++r) {
          float v = fmaxf(acc[i][j2][r] + bias, 0.f);
          h0[(size_t)(r0 + r) * 256 + gcol] = (_Float16)v;
          el1p[i][r] += wlv * v;
          er1p[i][r] += wrv * v;
        }
      }
    }
  }
  // reduce partial el1/er1 over the 16 col-lanes (cl); rows depend only on (wid,quad)
#pragma unroll
  for (int off = 1; off < 16; off <<= 1)
#pragma unroll
    for (int i = 0; i < 2; ++i)
#pragma unroll
      for (int r = 0; r < 4; ++r)
#pragma unroll
        for (int c = 0; c < 4; ++c) {
          el1p[i][r][c] += __shfl_xor(el1p[i][r][c], off);
          er1p[i][r][c] += __shfl_xor(er1p[i][r][c], off);
        }
  if (cl == 0) {
    for (int i = 0; i < 2; ++i)
      for (int r = 0; r < 4; ++r) {
        int row = m0 + wm + 16 * i + quad * 4 + r;
        *(f32x4*)(el1 + (size_t)row * 4) = el1p[i][r];
        if (row < N_DST1) *(f32x4*)(er1 + (size_t)row * 4) = er1p[i][r];
      }
  }
}

// out[m, 0:47] = log_softmax( axh1[m,:,:] (1024) @ BTs (1024 x 64, pre-scaled 0.25) + bmean )
__global__ __launch_bounds__(256) void gemm_out_kernel(
    const _Float16* __restrict__ axh1, const _Float16* __restrict__ BTs,
    const float* __restrict__ b1, float* __restrict__ out) {
  __shared__ _Float16 As[64 * 128];
  __shared__ _Float16 Bs[64 * 128];
  const int t = threadIdx.x, lane = t & 63, wid = t >> 6;
  const int m0 = blockIdx.x * 64;
  f32x4 acc[4] = {};
  for (int k0 = 0; k0 < 1024; k0 += 128) {
    for (int i = 0; i < 4; ++i) {
      int c = t + 256 * i, row = c >> 4, j = c & 15;
      int sw = ((j ^ (row & 7)) << 3);
      *(half8*)(&As[row * 128 + sw]) =
          *(const half8*)(axh1 + (size_t)(m0 + row) * 1024 + k0 + j * 8);
      *(half8*)(&Bs[row * 128 + sw]) =
          *(const half8*)(BTs + (size_t)row * 1024 + k0 + j * 8);
    }
    __syncthreads();
    const int wm = wid * 16;
    for (int ks = 0; ks < 4; ++ks) {
      int kc = ks * 4 + (lane >> 4);
      int ra = wm + (lane & 15);
      half8 af = *(const half8*)(&As[ra * 128 + ((kc ^ (ra & 7)) << 3)]);
      for (int j2 = 0; j2 < 4; ++j2) {
        int rb = 16 * j2 + (lane & 15);
        half8 bf = *(const half8*)(&Bs[rb * 128 + ((kc ^ (rb & 7)) << 3)]);
        acc[j2] = __builtin_amdgcn_mfma_f32_16x16x32_f16(af, bf, acc[j2], 0, 0, 0);
      }
    }
    __syncthreads();
  }
  int quad = lane >> 4, cl = lane & 15;
  float bm[3];
  for (int j2 = 0; j2 < 3; ++j2) {
    int col = 16 * j2 + cl;
    bm[j2] = (col < 47) ? 0.25f * (b1[col] + b1[col + 47] + b1[col + 94] + b1[col + 141]) : 0.f;
  }
  for (int r = 0; r < 4; ++r) {
    int row = m0 + wid * 16 + quad * 4 + r;
    float v[3];
    float mx = -1e30f;
    for (int j2 = 0; j2 < 3; ++j2) {
      int col = 16 * j2 + cl;
      v[j2] = acc[j2][r] + bm[j2];
      if (col < 47) mx = fmaxf(mx, v[j2]);
    }
    for (int off = 8; off; off >>= 1) mx = fmaxf(mx, __shfl_xor(mx, off));
    float s = 0.f;
    for (int j2 = 0; j2 < 3; ++j2) {
      int col = 16 * j2 + cl;
      if (col < 47) s += __expf(v[j2] - mx);
    }
    for (int off = 8; off; off >>= 1) s += __shfl_xor(s, off);
    float lse = mx + __logf(s);
    for (int j2 = 0; j2 < 3; ++j2) {
      int col = 16 * j2 + cl;
      if (col < 47) out[(size_t)row * 47 + col] = v[j2] - lse;
    }
  }
}

extern "C" void kernel_launch(void* const* d_in, const int* in_sizes, int n_in,
                              void* d_out, int out_size, void* d_ws, size_t ws_size,
                              hipStream_t stream) {
  const float* x   = (const float*)d_in[0];
  const int* src0  = (const int*)d_in[1];
  const int* dst0  = (const int*)d_in[2];
  const int* src1  = (const int*)d_in[3];
  const int* dst1  = (const int*)d_in[4];
  const float* Ws0 = (const float*)d_in[5];
  const float* Wd0 = (const float*)d_in[6];
  const float* al0 = (const float*)d_in[7];
  const float* ar0 = (const float*)d_in[8];
  const float* b0  = (const float*)d_in[9];
  const float* Ws1 = (const float*)d_in[10];
  const float* Wd1 = (const float*)d_in[11];
  const float* al1 = (const float*)d_in[12];
  const float* ar1 = (const float*)d_in[13];
  const float* b1  = (const float*)d_in[14];

  char* w = (char*)d_ws;
  auto alloc = [&](size_t bytes) {
    char* p = w;
    w += (bytes + 255) & ~(size_t)255;
    return p;
  };
  _Float16* xh   = (_Float16*)alloc((size_t)N_SRC0 * 128 * 2);   // 128 MB
  _Float16* axh  = (_Float16*)alloc((size_t)N_DST0 * 512 * 2);   // 67 MB
  _Float16* h0   = (_Float16*)alloc((size_t)N_DST0 * 256 * 2);   // 33.5 MB
  _Float16* axh1 = (_Float16*)alloc((size_t)N_DST1 * 1024 * 2);  // 16.8 MB
  float* el0     = (float*)alloc((size_t)N_SRC0 * 4 * 4);
  float* er0     = (float*)alloc((size_t)N_DST0 * 4 * 4);
  float* el1     = (float*)alloc((size_t)N_DST0 * 4 * 4);
  float* er1     = (float*)alloc((size_t)N_DST1 * 4 * 4);
  float* alpha0  = (float*)alloc((size_t)E0 * 4 * 4);            // 16.8 MB
  float* alpha1  = (float*)alloc((size_t)E1 * 4 * 4);            // 2.1 MB
  int* seg0      = (int*)alloc((size_t)(N_DST0 + 1) * 4);
  int* seg1      = (int*)alloc((size_t)(N_DST1 + 1) * 4);
  _Float16* BT0  = (_Float16*)alloc(256 * 128 * 2);
  _Float16* BTs  = (_Float16*)alloc(64 * 1024 * 2);
  _Float16* WLR0 = (_Float16*)alloc(16 * 128 * 2);
  float* wl0     = (float*)alloc(128 * 4 * 4);
  float* wr0     = (float*)alloc(128 * 4 * 4);
  float* wl1     = (float*)alloc(256 * 4 * 4);
  float* wr1     = (float*)alloc(256 * 4 * 4);

  collapse_kernel<<<2, 256, 0, stream>>>(Ws0, al0, wl0, 128, 64);
  collapse_kernel<<<2, 256, 0, stream>>>(Wd0, ar0, wr0, 128, 64);
  collapse_kernel<<<4, 256, 0, stream>>>(Ws1, al1, wl1, 256, 47);
  collapse_kernel<<<4, 256, 0, stream>>>(Wd1, ar1, wr1, 256, 47);
  wlr_stack_kernel<<<8, 256, 0, stream>>>(wl0, wr0, WLR0, 128);
  transposeW_kernel<<<128, 256, 0, stream>>>(Ws0, BT0, 128, 256);
  wstack_kernel<<<256, 256, 0, stream>>>(Ws1, BTs);
  seg_starts_kernel<<<(E0 + 1 + 255) / 256, 256, 0, stream>>>(dst0, E0, N_DST0, seg0);
  seg_starts_kernel<<<(E1 + 1 + 255) / 256, 256, 0, stream>>>(dst1, E1, N_DST1, seg1);
  cvt_elr_mfma_kernel<<<(N_SRC0 + 127) / 128, 256, 0, stream>>>(x, WLR0, xh, el0, er0,
                                                                N_SRC0, N_DST0);
  score_kernel<<<E0 / 256, 256, 0, stream>>>(src0, dst0, el0, er0, alpha0, E0);
  agg0w_kernel<<<N_DST0 / 4, 256, 0, stream>>>(src0, seg0, alpha0, xh, axh);
  gemm_h0_kernel<<<N_DST0 / 128, 256, 0, stream>>>(axh, BT0, b0, wl1, wr1, h0, el1, er1);
  score_kernel<<<E1 / 256, 256, 0, stream>>>(src1, dst1, el1, er1, alpha1, E1);
  agg1w_kernel<<<N_DST1 / 4, 256, 0, stream>>>(src1, seg1, alpha1, h0, axh1);
  gemm_out_kernel<<<N_DST1 / 64, 256, 0, stream>>>(axh1, BTs, b1, (float*)d_out);
}

// Round 3
// 544.302 us; speedup vs baseline: 1.1790x; 1.1790x over previous
//
#include <hip/hip_runtime.h>

typedef _Float16 half8  __attribute__((ext_vector_type(8)));
typedef _Float16 half4v __attribute__((ext_vector_type(4)));
typedef float    f32x4  __attribute__((ext_vector_type(4)));

#define GAT_SLOPE 0.2f
#define N_SRC0 500000
#define N_DST0 65536
#define N_DST1 8192
#define E0 1048576
#define E1 131072
#define H 4

__device__ __forceinline__ float leaky(float x) { return x >= 0.f ? x : GAT_SLOPE * x; }

// One kernel for all setup work, flat-index region dispatch:
// R0 [0,65536):        BTs[n*1024+h*256+k] = (n<47) ? 0.25*Ws1[k*188+h*47+n] : 0
// R1 [+32768):         BT0[n*128+k] = fp16(Ws0[k*256+n])
// R2 [+2048):          WLR0[n*128+k] = n<4: dot64(Ws0 row, al0) ; n<8: dot64(Wd0,ar0); else 0
// R3 [+1024):          wl1[k*4+h] = dot47(Ws1, al1)
// R4 [+1024):          wr1[k*4+h] = dot47(Wd1, ar1)
// R5 [+E0+1):          seg0 starts
// R6 [+E1+1):          seg1 starts
__global__ __launch_bounds__(256) void prep_kernel(
    const float* __restrict__ Ws0, const float* __restrict__ Wd0,
    const float* __restrict__ al0, const float* __restrict__ ar0,
    const float* __restrict__ Ws1, const float* __restrict__ Wd1,
    const float* __restrict__ al1, const float* __restrict__ ar1,
    const int* __restrict__ dst0, const int* __restrict__ dst1,
    _Float16* __restrict__ BTs, _Float16* __restrict__ BT0,
    _Float16* __restrict__ WLR0, float* __restrict__ wl1, float* __restrict__ wr1,
    int* __restrict__ seg0, int* __restrict__ seg1) {
  int i = blockIdx.x * 256 + threadIdx.x;
  if (i < 65536) {
    int n = i >> 10, kk = i & 1023, h = kk >> 8, k = kk & 255;
    BTs[i] = (n < 47) ? (_Float16)(0.25f * Ws1[(size_t)k * 188 + h * 47 + n]) : (_Float16)0.f;
    return;
  }
  i -= 65536;
  if (i < 32768) {
    int nrow = i >> 7, k = i & 127;
    BT0[i] = (_Float16)Ws0[(size_t)k * 256 + nrow];
    return;
  }
  i -= 32768;
  if (i < 2048) {
    int n = i >> 7, k = i & 127;
    float v = 0.f;
    if (n < 4) {
      for (int d = 0; d < 64; ++d) v += Ws0[(size_t)k * 256 + n * 64 + d] * al0[n * 64 + d];
    } else if (n < 8) {
      int h = n - 4;
      for (int d = 0; d < 64; ++d) v += Wd0[(size_t)k * 256 + h * 64 + d] * ar0[h * 64 + d];
    }
    WLR0[i] = (_Float16)v;
    return;
  }
  i -= 2048;
  if (i < 1024) {
    int k = i >> 2, h = i & 3;
    float v = 0.f;
    for (int d = 0; d < 47; ++d) v += Ws1[(size_t)k * 188 + h * 47 + d] * al1[h * 47 + d];
    wl1[i] = v;
    return;
  }
  i -= 1024;
  if (i < 1024) {
    int k = i >> 2, h = i & 3;
    float v = 0.f;
    for (int d = 0; d < 47; ++d) v += Wd1[(size_t)k * 188 + h * 47 + d] * ar1[h * 47 + d];
    wr1[i] = v;
    return;
  }
  i -= 1024;
  if (i <= E0) {
    int lo = (i == 0) ? 0 : dst0[i - 1] + 1;
    int hi = (i == E0) ? N_DST0 : dst0[i];
    for (int d = lo; d <= hi; ++d) seg0[d] = i;
    return;
  }
  i -= (E0 + 1);
  if (i <= E1) {
    int lo = (i == 0) ? 0 : dst1[i - 1] + 1;
    int hi = (i == E1) ? N_DST1 : dst1[i];
    for (int d = lo; d <= hi; ++d) seg1[d] = i;
  }
}
#define PREP_TOTAL (65536 + 32768 + 2048 + 1024 + 1024 + (E0 + 1) + (E1 + 1))

// streaming: x fp32 -> xh fp16 (global), + MFMA el0/er0 = x @ WLR0(128x16)
__global__ __launch_bounds__(256) void cvt_elr_mfma_kernel(
    const float* __restrict__ x, const _Float16* __restrict__ WLR,
    _Float16* __restrict__ xh, float* __restrict__ el, float* __restrict__ er,
    int M, int n_dst) {
  __shared__ _Float16 As[128 * 128];
  const int t = threadIdx.x, lane = t & 63, wid = t >> 6;
  const int m0 = blockIdx.x * 128;
  for (int i = 0; i < 8; ++i) {
    int c = t + 256 * i;
    int row = c >> 4, j = c & 15;
    int gr = m0 + row;
    half8 va = {};
    if (gr < M) {
      float4 f0 = *(const float4*)(x + (size_t)gr * 128 + j * 8);
      float4 f1 = *(const float4*)(x + (size_t)gr * 128 + j * 8 + 4);
      va[0] = (_Float16)f0.x; va[1] = (_Float16)f0.y;
      va[2] = (_Float16)f0.z; va[3] = (_Float16)f0.w;
      va[4] = (_Float16)f1.x; va[5] = (_Float16)f1.y;
      va[6] = (_Float16)f1.z; va[7] = (_Float16)f1.w;
      *(half8*)(xh + (size_t)gr * 128 + j * 8) = va;
    }
    *(half8*)(&As[row * 128 + ((j ^ (row & 7)) << 3)]) = va;
  }
  half8 bf[4];
  for (int kc = 0; kc < 4; ++kc)
    bf[kc] = *(const half8*)(WLR + (lane & 15) * 128 + kc * 32 + (lane >> 4) * 8);
  __syncthreads();
  f32x4 acc[2] = {};
  for (int rt = 0; rt < 2; ++rt) {
    int row = (wid * 2 + rt) * 16 + (lane & 15);
    for (int kc = 0; kc < 4; ++kc) {
      int chunk = kc * 4 + (lane >> 4);
      half8 af = *(const half8*)(&As[row * 128 + ((chunk ^ (row & 7)) << 3)]);
      acc[rt] = __builtin_amdgcn_mfma_f32_16x16x32_f16(af, bf[kc], acc[rt], 0, 0, 0);
    }
  }
  int col = lane & 15, quad = lane >> 4;
  for (int rt = 0; rt < 2; ++rt)
    for (int r = 0; r < 4; ++r) {
      int row = m0 + (wid * 2 + rt) * 16 + quad * 4 + r;
      if (row < M) {
        if (col < 4) el[(size_t)row * 4 + col] = acc[rt][r];
        else if (col < 8 && row < n_dst) er[(size_t)row * 4 + col - 4] = acc[rt][r];
      }
    }
}

// layer-0 aggregation, wave-per-node, INLINE score (no alpha round-trip):
// pass A: lane i computes alpha_i = exp(leaky(el[src_i]+er[n])) in regs, butterfly-sum
// pass B: two 32-lane groups stream edges; alpha + src via __shfl from owning lane
__global__ __launch_bounds__(256) void agg0s_kernel(
    const int* __restrict__ src, const int* __restrict__ seg,
    const float* __restrict__ el, const float* __restrict__ er,
    const _Float16* __restrict__ xh, _Float16* __restrict__ axh) {
  const int lane = threadIdx.x & 63, w = threadIdx.x >> 6;
  const int n = blockIdx.x * 4 + w;
  int s0 = seg[n], len = seg[n + 1] - s0;
  float4 erv = *(const float4*)(er + (size_t)n * 4);
  float a0 = 0.f, a1 = 0.f, a2 = 0.f, a3 = 0.f;
  float t0 = 0.f, t1 = 0.f, t2 = 0.f, t3 = 0.f;
  int sreg = 0;
  if (lane < len) {
    sreg = src[s0 + lane];
    float4 e4 = *(const float4*)(el + (size_t)sreg * 4);
    a0 = __expf(leaky(e4.x + erv.x)); a1 = __expf(leaky(e4.y + erv.y));
    a2 = __expf(leaky(e4.z + erv.z)); a3 = __expf(leaky(e4.w + erv.w));
    t0 = a0; t1 = a1; t2 = a2; t3 = a3;
  }
  for (int idx = 64 + lane; idx < len; idx += 64) {  // Poisson(16) tail: ~never
    int s = src[s0 + idx];
    float4 e4 = *(const float4*)(el + (size_t)s * 4);
    t0 += __expf(leaky(e4.x + erv.x)); t1 += __expf(leaky(e4.y + erv.y));
    t2 += __expf(leaky(e4.z + erv.z)); t3 += __expf(leaky(e4.w + erv.w));
  }
#pragma unroll
  for (int off = 32; off; off >>= 1) {
    t0 += __shfl_xor(t0, off); t1 += __shfl_xor(t1, off);
    t2 += __shfl_xor(t2, off); t3 += __shfl_xor(t3, off);
  }
  float si0 = t0 > 0.f ? 1.f / t0 : 0.f;
  float si1 = t1 > 0.f ? 1.f / t1 : 0.f;
  float si2 = t2 > 0.f ? 1.f / t2 : 0.f;
  float si3 = t3 > 0.f ? 1.f / t3 : 0.f;
  const int g = lane >> 5, ci = lane & 31;
  float A[4][4] = {};
  int iters = (len + 1) >> 1;
  for (int k = 0; k < iters; ++k) {
    int idx = g + 2 * k;
    int sl = idx < 64 ? idx : 0;
    float ah0 = __shfl(a0, sl), ah1 = __shfl(a1, sl);
    float ah2 = __shfl(a2, sl), ah3 = __shfl(a3, sl);
    int sidx = __shfl(sreg, sl);
    if (idx >= 64 && idx < len) {
      sidx = src[s0 + idx];
      float4 e4 = *(const float4*)(el + (size_t)sidx * 4);
      ah0 = __expf(leaky(e4.x + erv.x)); ah1 = __expf(leaky(e4.y + erv.y));
      ah2 = __expf(leaky(e4.z + erv.z)); ah3 = __expf(leaky(e4.w + erv.w));
    }
    if (idx < len) {
      half4v xv = *(const half4v*)(xh + (size_t)sidx * 128 + ci * 4);
#pragma unroll
      for (int c = 0; c < 4; ++c) {
        float xc = (float)xv[c];
        A[0][c] += ah0 * xc; A[1][c] += ah1 * xc;
        A[2][c] += ah2 * xc; A[3][c] += ah3 * xc;
      }
    }
  }
#pragma unroll
  for (int h = 0; h < 4; ++h)
#pragma unroll
    for (int c = 0; c < 4; ++c) A[h][c] += __shfl_xor(A[h][c], 32);
  if (g == 0) {
    float si[4] = {si0, si1, si2, si3};
#pragma unroll
    for (int h = 0; h < 4; ++h) {
      half4v o;
#pragma unroll
      for (int c = 0; c < 4; ++c) o[c] = (_Float16)(A[h][c] * si[h]);
      *(half4v*)(axh + ((size_t)n * 4 + h) * 128 + ci * 4) = o;
    }
  }
}

// layer-1 aggregation: same structure, 8 ch/lane over 256 cols
__global__ __launch_bounds__(256) void agg1s_kernel(
    const int* __restrict__ src, const int* __restrict__ seg,
    const float* __restrict__ el, const float* __restrict__ er,
    const _Float16* __restrict__ h0, _Float16* __restrict__ axh1) {
  const int lane = threadIdx.x & 63, w = threadIdx.x >> 6;
  const int n = blockIdx.x * 4 + w;
  int s0 = seg[n], len = seg[n + 1] - s0;
  float4 erv = *(const float4*)(er + (size_t)n * 4);
  float a0 = 0.f, a1 = 0.f, a2 = 0.f, a3 = 0.f;
  float t0 = 0.f, t1 = 0.f, t2 = 0.f, t3 = 0.f;
  int sreg = 0;
  if (lane < len) {
    sreg = src[s0 + lane];
    float4 e4 = *(const float4*)(el + (size_t)sreg * 4);
    a0 = __expf(leaky(e4.x + erv.x)); a1 = __expf(leaky(e4.y + erv.y));
    a2 = __expf(leaky(e4.z + erv.z)); a3 = __expf(leaky(e4.w + erv.w));
    t0 = a0; t1 = a1; t2 = a2; t3 = a3;
  }
  for (int idx = 64 + lane; idx < len; idx += 64) {
    int s = src[s0 + idx];
    float4 e4 = *(const float4*)(el + (size_t)s * 4);
    t0 += __expf(leaky(e4.x + erv.x)); t1 += __expf(leaky(e4.y + erv.y));
    t2 += __expf(leaky(e4.z + erv.z)); t3 += __expf(leaky(e4.w + erv.w));
  }
#pragma unroll
  for (int off = 32; off; off >>= 1) {
    t0 += __shfl_xor(t0, off); t1 += __shfl_xor(t1, off);
    t2 += __shfl_xor(t2, off); t3 += __shfl_xor(t3, off);
  }
  float si0 = t0 > 0.f ? 1.f / t0 : 0.f;
  float si1 = t1 > 0.f ? 1.f / t1 : 0.f;
  float si2 = t2 > 0.f ? 1.f / t2 : 0.f;
  float si3 = t3 > 0.f ? 1.f / t3 : 0.f;
  const int g = lane >> 5, ci = lane & 31;
  float A[4][8] = {};
  int iters = (len + 1) >> 1;
  for (int k = 0; k < iters; ++k) {
    int idx = g + 2 * k;
    int sl = idx < 64 ? idx : 0;
    float ah0 = __shfl(a0, sl), ah1 = __shfl(a1, sl);
    float ah2 = __shfl(a2, sl), ah3 = __shfl(a3, sl);
    int sidx = __shfl(sreg, sl);
    if (idx >= 64 && idx < len) {
      sidx = src[s0 + idx];
      float4 e4 = *(const float4*)(el + (size_t)sidx * 4);
      ah0 = __expf(leaky(e4.x + erv.x)); ah1 = __expf(leaky(e4.y + erv.y));
      ah2 = __expf(leaky(e4.z + erv.z)); ah3 = __expf(leaky(e4.w + erv.w));
    }
    if (idx < len) {
      half8 xv = *(const half8*)(h0 + (size_t)sidx * 256 + ci * 8);
#pragma unroll
      for (int c = 0; c < 8; ++c) {
        float xc = (float)xv[c];
        A[0][c] += ah0 * xc; A[1][c] += ah1 * xc;
        A[2][c] += ah2 * xc; A[3][c] += ah3 * xc;
      }
    }
  }
#pragma unroll
  for (int h = 0; h < 4; ++h)
#pragma unroll
    for (int c = 0; c < 8; ++c) A[h][c] += __shfl_xor(A[h][c], 32);
  if (g == 0) {
    float si[4] = {si0, si1, si2, si3};
#pragma unroll
    for (int h = 0; h < 4; ++h) {
      half8 o;
#pragma unroll
      for (int c = 0; c < 8; ++c) o[c] = (_Float16)(A[h][c] * si[h]);
      *(half8*)(axh1 + ((size_t)n * 4 + h) * 256 + ci * 8) = o;
    }
  }
}

// h0[m, h*64+d] = relu( axh[m,h,:] @ BT0[h*64+d, :] + b0 ), all 4 heads per block,
// FUSED epilogue: el1[m][hh] = sum_c h0[m,c]*wl1[c*4+hh], er1 likewise (rows < N_DST1).
__global__ __launch_bounds__(256) void gemm_h0_kernel(
    const _Float16* __restrict__ axh, const _Float16* __restrict__ BT,
    const float* __restrict__ b, const float* __restrict__ wl1,
    const float* __restrict__ wr1, _Float16* __restrict__ h0,
    float* __restrict__ el1, float* __restrict__ er1) {
  __shared__ _Float16 As[128 * 128];
  __shared__ _Float16 Bs[64 * 128];
  const int t = threadIdx.x, lane = t & 63, wid = t >> 6;
  const int m0 = blockIdx.x * 128;
  const int cl = lane & 15, quad = lane >> 4;
  const int wm = wid * 32;
  f32x4 el1p[2][4] = {}, er1p[2][4] = {};
  for (int h = 0; h < 4; ++h) {
    for (int i = 0; i < 8; ++i) {
      int c = t + 256 * i, row = c >> 4, j = c & 15;
      int sw = ((j ^ (row & 7)) << 3);
      *(half8*)(&As[row * 128 + sw]) =
          *(const half8*)(axh + ((size_t)(m0 + row) * 4 + h) * 128 + j * 8);
    }
    for (int i = 0; i < 4; ++i) {
      int c = t + 256 * i, row = c >> 4, j = c & 15;
      int sw = ((j ^ (row & 7)) << 3);
      *(half8*)(&Bs[row * 128 + sw]) =
          *(const half8*)(BT + (size_t)(h * 64 + row) * 128 + j * 8);
    }
    __syncthreads();
    f32x4 acc[2][4] = {};
    for (int ks = 0; ks < 4; ++ks) {
      int kc = ks * 4 + quad;
      half8 af[2], bf[4];
      for (int i = 0; i < 2; ++i) {
        int ra = wm + 16 * i + cl;
        af[i] = *(const half8*)(&As[ra * 128 + ((kc ^ (ra & 7)) << 3)]);
      }
      for (int j2 = 0; j2 < 4; ++j2) {
        int rb = 16 * j2 + cl;
        bf[j2] = *(const half8*)(&Bs[rb * 128 + ((kc ^ (rb & 7)) << 3)]);
      }
      for (int i = 0; i < 2; ++i)
        for (int j2 = 0; j2 < 4; ++j2)
          acc[i][j2] = __builtin_amdgcn_mfma_f32_16x16x32_f16(af[i], bf[j2], acc[i][j2], 0, 0, 0);
    }
    __syncthreads();
    for (int j2 = 0; j2 < 4; ++j2) {
      int gcol = h * 64 + 16 * j2 + cl;
      float bias = b[gcol];
      f32x4 wlv = *(const f32x4*)(wl1 + (size_t)gcol * 4);
      f32x4 wrv = *(const f32x4*)(wr1 + (size_t)gcol * 4);
      for (int i = 0; i < 2; ++i) {
        int r0 = m0 + wm + 16 * i + quad * 4;
        for (int r = 0; r < 4; ++r) {
          float v = fmaxf(acc[i][j2][r] + bias, 0.f);
          h0[(size_t)(r0 + r) * 256 + gcol] = (_Float16)v;
          el1p[i][r] += wlv * v;
          er1p[i][r] += wrv * v;
        }
      }
    }
  }
#pragma unroll
  for (int off = 1; off < 16; off <<= 1)
#pragma unroll
    for (int i = 0; i < 2; ++i)
#pragma unroll
      for (int r = 0; r < 4; ++r)
#pragma unroll
        for (int c = 0; c < 4; ++c) {
          el1p[i][r][c] += __shfl_xor(el1p[i][r][c], off);
          er1p[i][r][c] += __shfl_xor(er1p[i][r][c], off);
        }
  if (cl == 0) {
    for (int i = 0; i < 2; ++i)
      for (int r = 0; r < 4; ++r) {
        int row = m0 + wm + 16 * i + quad * 4 + r;
        *(f32x4*)(el1 + (size_t)row * 4) = el1p[i][r];
        if (row < N_DST1) *(f32x4*)(er1 + (size_t)row * 4) = er1p[i][r];
      }
  }
}

// out[m, 0:47] = log_softmax( axh1[m,:,:] (1024) @ BTs (1024 x 64, pre-scaled 0.25) + bmean )
__global__ __launch_bounds__(256) void gemm_out_kernel(
    const _Float16* __restrict__ axh1, const _Float16* __restrict__ BTs,
    const float* __restrict__ b1, float* __restrict__ out) {
  __shared__ _Float16 As[64 * 128];
  __shared__ _Float16 Bs[64 * 128];
  const int t = threadIdx.x, lane = t & 63, wid = t >> 6;
  const int m0 = blockIdx.x * 64;
  f32x4 acc[4] = {};
  for (int k0 = 0; k0 < 1024; k0 += 128) {
    for (int i = 0; i < 4; ++i) {
      int c = t + 256 * i, row = c >> 4, j = c & 15;
      int sw = ((j ^ (row & 7)) << 3);
      *(half8*)(&As[row * 128 + sw]) =
          *(const half8*)(axh1 + (size_t)(m0 + row) * 1024 + k0 + j * 8);
      *(half8*)(&Bs[row * 128 + sw]) =
          *(const half8*)(BTs + (size_t)row * 1024 + k0 + j * 8);
    }
    __syncthreads();
    const int wm = wid * 16;
    for (int ks = 0; ks < 4; ++ks) {
      int kc = ks * 4 + (lane >> 4);
      int ra = wm + (lane & 15);
      half8 af = *(const half8*)(&As[ra * 128 + ((kc ^ (ra & 7)) << 3)]);
      for (int j2 = 0; j2 < 4; ++j2) {
        int rb = 16 * j2 + (lane & 15);
        half8 bf = *(const half8*)(&Bs[rb * 128 + ((kc ^ (rb & 7)) << 3)]);
        acc[j2] = __builtin_amdgcn_mfma_f32_16x16x32_f16(af, bf, acc[j2], 0, 0, 0);
      }
    }
    __syncthreads();
  }
  int quad = lane >> 4, cl = lane & 15;
  float bm[3];
  for (int j2 = 0; j2 < 3; ++j2) {
    int col = 16 * j2 + cl;
    bm[j2] = (col < 47) ? 0.25f * (b1[col] + b1[col + 47] + b1[col + 94] + b1[col + 141]) : 0.f;
  }
  for (int r = 0; r < 4; ++r) {
    int row = m0 + wid * 16 + quad * 4 + r;
    float v[3];
    float mx = -1e30f;
    for (int j2 = 0; j2 < 3; ++j2) {
      int col = 16 * j2 + cl;
      v[j2] = acc[j2][r] + bm[j2];
      if (col < 47) mx = fmaxf(mx, v[j2]);
    }
    for (int off = 8; off; off >>= 1) mx = fmaxf(mx, __shfl_xor(mx, off));
    float s = 0.f;
    for (int j2 = 0; j2 < 3; ++j2) {
      int col = 16 * j2 + cl;
      if (col < 47) s += __expf(v[j2] - mx);
    }
    for (int off = 8; off; off >>= 1) s += __shfl_xor(s, off);
    float lse = mx + __logf(s);
    for (int j2 = 0; j2 < 3; ++j2) {
      int col = 16 * j2 + cl;
      if (col < 47) out[(size_t)row * 47 + col] = v[j2] - lse;
    }
  }
}

extern "C" void kernel_launch(void* const* d_in, const int* in_sizes, int n_in,
                              void* d_out, int out_size, void* d_ws, size_t ws_size,
                              hipStream_t stream) {
  const float* x   = (const float*)d_in[0];
  const int* src0  = (const int*)d_in[1];
  const int* dst0  = (const int*)d_in[2];
  const int* src1  = (const int*)d_in[3];
  const int* dst1  = (const int*)d_in[4];
  const float* Ws0 = (const float*)d_in[5];
  const float* Wd0 = (const float*)d_in[6];
  const float* al0 = (const float*)d_in[7];
  const float* ar0 = (const float*)d_in[8];
  const float* b0  = (const float*)d_in[9];
  const float* Ws1 = (const float*)d_in[10];
  const float* Wd1 = (const float*)d_in[11];
  const float* al1 = (const float*)d_in[12];
  const float* ar1 = (const float*)d_in[13];
  const float* b1  = (const float*)d_in[14];

  char* w = (char*)d_ws;
  auto alloc = [&](size_t bytes) {
    char* p = w;
    w += (bytes + 255) & ~(size_t)255;
    return p;
  };
  _Float16* xh   = (_Float16*)alloc((size_t)N_SRC0 * 128 * 2);   // 128 MB
  _Float16* axh  = (_Float16*)alloc((size_t)N_DST0 * 512 * 2);   // 67 MB
  _Float16* h0   = (_Float16*)alloc((size_t)N_DST0 * 256 * 2);   // 33.5 MB
  _Float16* axh1 = (_Float16*)alloc((size_t)N_DST1 * 1024 * 2);  // 16.8 MB
  float* el0     = (float*)alloc((size_t)N_SRC0 * 4 * 4);
  float* er0     = (float*)alloc((size_t)N_DST0 * 4 * 4);
  float* el1     = (float*)alloc((size_t)N_DST0 * 4 * 4);
  float* er1     = (float*)alloc((size_t)N_DST1 * 4 * 4);
  int* seg0      = (int*)alloc((size_t)(N_DST0 + 1) * 4);
  int* seg1      = (int*)alloc((size_t)(N_DST1 + 1) * 4);
  _Float16* BT0  = (_Float16*)alloc(256 * 128 * 2);
  _Float16* BTs  = (_Float16*)alloc(64 * 1024 * 2);
  _Float16* WLR0 = (_Float16*)alloc(16 * 128 * 2);
  float* wl1     = (float*)alloc(256 * 4 * 4);
  float* wr1     = (float*)alloc(256 * 4 * 4);

  prep_kernel<<<(PREP_TOTAL + 255) / 256, 256, 0, stream>>>(
      Ws0, Wd0, al0, ar0, Ws1, Wd1, al1, ar1, dst0, dst1,
      BTs, BT0, WLR0, wl1, wr1, seg0, seg1);
  cvt_elr_mfma_kernel<<<(N_SRC0 + 127) / 128, 256, 0, stream>>>(x, WLR0, xh, el0, er0,
                                                                N_SRC0, N_DST0);
  agg0s_kernel<<<N_DST0 / 4, 256, 0, stream>>>(src0, seg0, el0, er0, xh, axh);
  gemm_h0_kernel<<<N_DST0 / 128, 256, 0, stream>>>(axh, BT0, b0, wl1, wr1, h0, el1, er1);
  agg1s_kernel<<<N_DST1 / 4, 256, 0, stream>>>(src1, seg1, el1, er1, h0, axh1);
  gemm_out_kernel<<<N_DST1 / 64, 256, 0, stream>>>(axh1, BTs, b1, (float*)d_out);
}